// Round 9
// baseline (276.746 us; speedup 1.0000x reference)
//
#include <hip/hip_runtime.h>
#include <hip/hip_bf16.h>

#define LL 512
#define DD 1024
#define HH 8
#define DKK 128
#define QQ 256
#define CCC 128
#define TTT 128
#define RR 50
#define FFF 4096

typedef __attribute__((ext_vector_type(8))) short short8;
typedef __attribute__((ext_vector_type(4))) float float4v;

__device__ __forceinline__ unsigned short f2bu(float f) {
  __hip_bfloat16 h = __float2bfloat16(f);
  unsigned short u; __builtin_memcpy(&u, &h, 2); return u;
}
__device__ __forceinline__ float b2f(unsigned short u) {
  unsigned int v = ((unsigned int)u) << 16;
  float f; __builtin_memcpy(&f, &v, 4); return f;
}
__device__ __forceinline__ int4 cvt8(float4 x, float4 y) {
  int4 o;
  o.x = (int)f2bu(x.x) | ((int)f2bu(x.y) << 16);
  o.y = (int)f2bu(x.z) | ((int)f2bu(x.w) << 16);
  o.z = (int)f2bu(y.x) | ((int)f2bu(y.y) << 16);
  o.w = (int)f2bu(y.z) | ((int)f2bu(y.w) << 16);
  return o;
}

// barrier that only drains LDS (lgkmcnt(0)); global loads stay in flight.
// 0xC07F = vmcnt(63) expcnt(7) lgkmcnt(0) on gfx9-family encoding.
__device__ __forceinline__ void lds_barrier() {
  __builtin_amdgcn_sched_barrier(0);
  __builtin_amdgcn_s_waitcnt(0xC07F);
  __builtin_amdgcn_s_barrier();
  __builtin_amdgcn_sched_barrier(0);
}

// explicit-scalar load/store macros: NO arrays, NO pointer params -> no scratch.
#define LOADSET(A0,A1,B0,B1,F0,F1,F2,F3,itv) { int k0v = (itv) << 6;          \
  A0 = *(const int4*)(Az + (size_t)(bm + r)*lda + k0v + gc*8);                \
  A1 = *(const int4*)(Az + (size_t)(bm + 32 + r)*lda + k0v + gc*8);           \
  if constexpr (!CONVB) {                                                     \
    B0 = *(const int4*)(Bz16 + (size_t)(bnb + r)*ldb + k0v + gc*8);           \
    if constexpr (NB > 1)                                                     \
      B1 = *(const int4*)(Bz16 + (size_t)(bnb + 32 + r)*ldb + k0v + gc*8);    \
  } else {                                                                    \
    F0 = *(const float4*)(Bz32 + (size_t)(bnb + r)*ldb + k0v + gc*8);         \
    F1 = *(const float4*)(Bz32 + (size_t)(bnb + r)*ldb + k0v + gc*8 + 4);     \
    if constexpr (NB > 1) {                                                   \
      F2 = *(const float4*)(Bz32 + (size_t)(bnb + 32 + r)*ldb + k0v + gc*8);  \
      F3 = *(const float4*)(Bz32 + (size_t)(bnb + 32 + r)*ldb + k0v + gc*8 + 4); } } }

#define STORESET2(basep,A0,A1,B0,B1,F0,F1,F2,F3) {                            \
  char* bse = (basep);                                                        \
  *(int4*)(bse + r*128 + sl*16) = A0;                                         \
  *(int4*)(bse + (32 + r)*128 + sl*16) = A1;                                  \
  if constexpr (!CONVB) {                                                     \
    *(int4*)(bse + ABYTES + r*128 + sl*16) = B0;                              \
    if constexpr (NB > 1)                                                     \
      *(int4*)(bse + ABYTES + (32 + r)*128 + sl*16) = B1;                     \
  } else {                                                                    \
    *(int4*)(bse + ABYTES + r*128 + sl*16) = cvt8(F0, F1);                    \
    if constexpr (NB > 1)                                                     \
      *(int4*)(bse + ABYTES + (32 + r)*128 + sl*16) = cvt8(F2, F3); } }

// ---------------- LayerNorm: fp32 in, bf16 out ----------------
__global__ __launch_bounds__(256) void ln_bf16_kernel(const float* __restrict__ x,
    const float* __restrict__ g, const float* __restrict__ b,
    unsigned short* __restrict__ y)
{
  int row = blockIdx.x, t = threadIdx.x;
  const float4 xv = ((const float4*)(x + row*DD))[t];
  float s  = xv.x+xv.y+xv.z+xv.w;
  float ss = xv.x*xv.x+xv.y*xv.y+xv.z*xv.z+xv.w*xv.w;
  __shared__ float rs[256], rss[256];
  rs[t]=s; rss[t]=ss; __syncthreads();
  for (int st=128; st>0; st>>=1){ if (t<st){ rs[t]+=rs[t+st]; rss[t]+=rss[t+st]; } __syncthreads(); }
  float mean = rs[0] * (1.0f/DD);
  float var  = rss[0]*(1.0f/DD) - mean*mean;
  float inv  = rsqrtf(var + 1e-5f);
  float4 gv = ((const float4*)g)[t], bv = ((const float4*)b)[t];
  ushort4 ov;
  ov.x = f2bu((xv.x-mean)*inv*gv.x + bv.x);
  ov.y = f2bu((xv.y-mean)*inv*gv.y + bv.y);
  ov.z = f2bu((xv.z-mean)*inv*gv.z + bv.z);
  ov.w = f2bu((xv.w-mean)*inv*gv.w + bv.w);
  ((ushort4*)(y + row*DD))[t] = ov;
}

// ---------------- LayerNorm + out += b2 (split-K init), fp32 io ----------------
__global__ __launch_bounds__(256) void ln_bf16_addb_kernel(float* __restrict__ x,
    const float* __restrict__ g, const float* __restrict__ b,
    const float* __restrict__ b2, unsigned short* __restrict__ y)
{
  int row = blockIdx.x, t = threadIdx.x;
  const float4 xv = ((const float4*)(x + row*DD))[t];
  float s  = xv.x+xv.y+xv.z+xv.w;
  float ss = xv.x*xv.x+xv.y*xv.y+xv.z*xv.z+xv.w*xv.w;
  __shared__ float rs[256], rss[256];
  rs[t]=s; rss[t]=ss; __syncthreads();
  for (int st=128; st>0; st>>=1){ if (t<st){ rs[t]+=rs[t+st]; rss[t]+=rss[t+st]; } __syncthreads(); }
  float mean = rs[0] * (1.0f/DD);
  float var  = rss[0]*(1.0f/DD) - mean*mean;
  float inv  = rsqrtf(var + 1e-5f);
  float4 gv = ((const float4*)g)[t], bv = ((const float4*)b)[t];
  ushort4 ov;
  ov.x = f2bu((xv.x-mean)*inv*gv.x + bv.x);
  ov.y = f2bu((xv.y-mean)*inv*gv.y + bv.y);
  ov.z = f2bu((xv.z-mean)*inv*gv.z + bv.z);
  ov.w = f2bu((xv.w-mean)*inv*gv.w + bv.w);
  ((ushort4*)(y + row*DD))[t] = ov;
  float4 b2v = ((const float4*)b2)[t];
  float4 nx; nx.x = xv.x+b2v.x; nx.y = xv.y+b2v.y; nx.z = xv.z+b2v.z; nx.w = xv.w+b2v.w;
  ((float4*)(x + row*DD))[t] = nx;
}

// ======== VGPR-staged pipelined bf16 MFMA GEMM (explicit scalars) ========
template<int BN, int CONVB, int ZK, int OUT_BF16, int RELU, int HAS_SRC, int HAS_BIAS>
__global__ __launch_bounds__(256) void gemm_pl(
    const unsigned short* __restrict__ A, int lda, size_t sAz,
    const void* __restrict__ Bv, int ldb, size_t sBz,
    const float* __restrict__ bias,
    const float* __restrict__ src, int ldsrc, size_t sSz,
    void* __restrict__ Cv, int ldc, size_t sCz,
    int K)
{
  constexpr int BM = 64;
  constexpr int WM = 32, WN = BN/2, FM = 2, FN = WN/16;
  constexpr int NB = BN/32;
  constexpr int ABYTES = BM*128, TILE = ABYTES + BN*128;
  __shared__ char lds[2*TILE];
  int t = threadIdx.x, w = t >> 6, l = t & 63;
  size_t z = blockIdx.z;
  const unsigned short* Az = A + z*sAz;
  const unsigned short* Bz16 = (const unsigned short*)Bv + (CONVB ? 0 : z*sBz);
  const float*          Bz32 = (const float*)Bv + (CONVB ? z*sBz : 0);
  int bm = blockIdx.y*BM, bn = blockIdx.x*BN;
  int bnb = bn;
  int wm = (w>>1)*WM, wn = (w&1)*WN;

  float4v acc[FM][FN];
  #pragma unroll
  for (int m=0;m<FM;++m)
    #pragma unroll
    for (int n=0;n<FN;++n) acc[m][n] = (float4v){0.f,0.f,0.f,0.f};

  int r = t >> 3, sl = t & 7;
  int gc = sl ^ (r & 7);
  int quad = l >> 4, lrow = l & 15;
  const int nit = K >> 6;           // even

  int4 pa0, pa1, pb0, pb1;  float4 pf0, pf1, pf2, pf3;   // ping
  int4 qa0, qa1, qb0, qb1;  float4 qf0, qf1, qf2, qf3;   // pong

  auto compute = [&](const char* base) {
    const char* ab = base;
    const char* bb = base + ABYTES;
    #pragma unroll
    for (int step=0; step<2; ++step) {
      int c = step*4 + quad;
      short8 af[FM], bf[FN];
      #pragma unroll
      for (int m=0;m<FM;++m) {
        int Rw = wm + m*16 + lrow;
        af[m] = *(const short8*)(ab + Rw*128 + ((c ^ (Rw & 7))*16));
      }
      #pragma unroll
      for (int n=0;n<FN;++n) {
        int Rw = wn + n*16 + lrow;
        bf[n] = *(const short8*)(bb + Rw*128 + ((c ^ (Rw & 7))*16));
      }
      #pragma unroll
      for (int m=0;m<FM;++m)
        #pragma unroll
        for (int n=0;n<FN;++n)
          acc[m][n] = __builtin_amdgcn_mfma_f32_16x16x32_bf16(af[m], bf[n], acc[m][n], 0, 0, 0);
    }
  };

  LOADSET(pa0,pa1,pb0,pb1,pf0,pf1,pf2,pf3, 0);
  LOADSET(qa0,qa1,qb0,qb1,qf0,qf1,qf2,qf3, 1);
  for (int it = 0; it < nit; it += 2) {
    STORESET2(lds, pa0,pa1,pb0,pb1,pf0,pf1,pf2,pf3);
    if (it + 2 < nit) LOADSET(pa0,pa1,pb0,pb1,pf0,pf1,pf2,pf3, it+2);
    lds_barrier();
    compute(lds);
    STORESET2(lds + TILE, qa0,qa1,qb0,qb1,qf0,qf1,qf2,qf3);
    if (it + 3 < nit) LOADSET(qa0,qa1,qb0,qb1,qf0,qf1,qf2,qf3, it+3);
    lds_barrier();
    compute(lds + TILE);
  }

  #pragma unroll
  for (int m=0;m<FM;++m)
    #pragma unroll
    for (int n=0;n<FN;++n)
      #pragma unroll
      for (int rg=0;rg<4;++rg) {
        int row = bm + wm + m*16 + quad*4 + rg;
        int col = bn + wn + n*16 + lrow;
        float vv = acc[m][n][rg];
        if (ZK) {
          atomicAdd(&((float*)Cv)[(size_t)row*ldc + col], vv);
        } else {
          if (HAS_BIAS) vv += bias[col];
          if (HAS_SRC)  vv += src[z*sSz + (size_t)row*ldsrc + col];
          if (RELU) vv = fmaxf(vv, 0.f);
          if (OUT_BF16) ((unsigned short*)Cv)[z*sCz + (size_t)row*ldc + col] = f2bu(vv);
          else          ((float*)Cv)[z*sCz + (size_t)row*ldc + col] = vv;
        }
      }
}

// ---------------- QKV GEMM: fp32 weights direct + head-scatter epilogue -----
__global__ __launch_bounds__(256) void gemm_qkv_pl(
    const unsigned short* __restrict__ A,
    const float* __restrict__ Wq, const float* __restrict__ Wk,
    const float* __restrict__ Wv,
    const float* __restrict__ bq, const float* __restrict__ bk,
    const float* __restrict__ bv,
    unsigned short* __restrict__ Qh, unsigned short* __restrict__ Kh,
    unsigned short* __restrict__ Vt)
{
  constexpr int BN = 64, CONVB = 1;
  constexpr int WM = 32, WN = 32, FM = 2, FN = 2;
  constexpr int NB = 2;
  constexpr int ABYTES = 64*128, TILE = ABYTES + BN*128;
  __shared__ char lds[2*TILE];
  int t = threadIdx.x, w = t >> 6, l = t & 63;
  int bm = blockIdx.y*64, bn = blockIdx.x*BN;
  int wm = (w>>1)*WM, wn = (w&1)*WN;
  const int lda = DD, ldb = DD, nit = DD >> 6;
  const unsigned short* Az = A;
  int part0 = bn >> 10;
  const float* Bz32 = (part0==0 ? Wq : part0==1 ? Wk : Wv) + (size_t)(bn & 1023)*DD;
  const unsigned short* Bz16 = nullptr; (void)Bz16;
  int bnb = 0;   // Bz32 already offset to tile base

  float4v acc[FM][FN];
  #pragma unroll
  for (int m=0;m<FM;++m)
    #pragma unroll
    for (int n=0;n<FN;++n) acc[m][n] = (float4v){0.f,0.f,0.f,0.f};

  int r = t >> 3, sl = t & 7;
  int gc = sl ^ (r & 7);
  int quad = l >> 4, lrow = l & 15;

  int4 pa0, pa1, pb0, pb1;  float4 pf0, pf1, pf2, pf3;
  int4 qa0, qa1, qb0, qb1;  float4 qf0, qf1, qf2, qf3;

  auto compute = [&](const char* base) {
    const char* ab = base;
    const char* bb = base + ABYTES;
    #pragma unroll
    for (int step=0; step<2; ++step) {
      int c = step*4 + quad;
      short8 af[FM], bf[FN];
      #pragma unroll
      for (int m=0;m<FM;++m) {
        int Rw = wm + m*16 + lrow;
        af[m] = *(const short8*)(ab + Rw*128 + ((c ^ (Rw & 7))*16));
      }
      #pragma unroll
      for (int n=0;n<FN;++n) {
        int Rw = wn + n*16 + lrow;
        bf[n] = *(const short8*)(bb + Rw*128 + ((c ^ (Rw & 7))*16));
      }
      #pragma unroll
      for (int m=0;m<FM;++m)
        #pragma unroll
        for (int n=0;n<FN;++n)
          acc[m][n] = __builtin_amdgcn_mfma_f32_16x16x32_bf16(af[m], bf[n], acc[m][n], 0, 0, 0);
    }
  };

  LOADSET(pa0,pa1,pb0,pb1,pf0,pf1,pf2,pf3, 0);
  LOADSET(qa0,qa1,qb0,qb1,qf0,qf1,qf2,qf3, 1);
  for (int it = 0; it < nit; it += 2) {
    STORESET2(lds, pa0,pa1,pb0,pb1,pf0,pf1,pf2,pf3);
    if (it + 2 < nit) LOADSET(pa0,pa1,pb0,pb1,pf0,pf1,pf2,pf3, it+2);
    lds_barrier();
    compute(lds);
    STORESET2(lds + TILE, qa0,qa1,qb0,qb1,qf0,qf1,qf2,qf3);
    if (it + 3 < nit) LOADSET(qa0,qa1,qb0,qb1,qf0,qf1,qf2,qf3, it+3);
    lds_barrier();
    compute(lds + TILE);
  }

  #pragma unroll
  for (int m=0;m<FM;++m)
    #pragma unroll
    for (int n=0;n<FN;++n)
      #pragma unroll
      for (int rg=0;rg<4;++rg) {
        int row = bm + wm + m*16 + quad*4 + rg;
        int col = bn + wn + n*16 + lrow;
        int part = col >> 10, hh = (col >> 7) & 7, d = col & 127;
        const float* bp = (part==0) ? bq : (part==1) ? bk : bv;
        float vv = acc[m][n][rg] + bp[col & 1023];
        unsigned short o = f2bu(vv);
        if (part == 0)      Qh[((size_t)hh*LL + row)*DKK + d] = o;
        else if (part == 1) Kh[((size_t)hh*LL + row)*DKK + d] = o;
        else                Vt[((size_t)hh*DKK + d)*LL + row] = o;
      }
}

// ---------------- qe + ql tables fused: one block per (i,h) ----------------
__global__ __launch_bounds__(64) void qtab_kernel(const unsigned short* __restrict__ Qh,
    const float* __restrict__ embk,
    const float* __restrict__ lqc, const float* __restrict__ lqt,
    const float* __restrict__ lcq, const float* __restrict__ ltq,
    float* __restrict__ qe, float* __restrict__ ql)
{
  int i = blockIdx.x, h = blockIdx.y, t = threadIdx.x;
  __shared__ float qrow[128];
  const unsigned short* qp = Qh + ((size_t)h*LL + i)*DKK;
  qrow[t] = b2f(qp[t]); qrow[t+64] = b2f(qp[t+64]);
  __syncthreads();
  if (t < RR) {
    float s = 0.f;
    #pragma unroll 8
    for (int d=0; d<128; ++d) s += qrow[d]*embk[t*128+d];
    qe[(i*HH+h)*RR + t] = s;
  } else if (t < RR + 12) {
    int u = t - RR;
    int tb = u/3, f = u - tb*3;
    const float* tab = (tb==0) ? lqc : (tb==1) ? lqt : (tb==2) ? lcq : ltq;
    const float* tr = tab + f*128;
    float s = 0.f;
    #pragma unroll 8
    for (int d=0; d<128; ++d) s += qrow[d]*tr[d];
    ql[((tb*LL + i)*HH + h)*3 + f] = s;
  }
}

// ======== fused bias + mask + softmax + pw/pf scatter + o2 epilogue ========
// one block per (i,h), 512 threads; S fp32 in, P bf16 in-place, o2 out.
__global__ __launch_bounds__(512) void softmax_pw_kernel(
    float* __restrict__ S,
    const float* __restrict__ qe, const float* __restrict__ ql,
    const float* __restrict__ qcr, const float* __restrict__ cqr,
    const float* __restrict__ qtr, const float* __restrict__ tqr,
    const int* __restrict__ ct,   const int* __restrict__ pred,
    const int* __restrict__ mask,
    const float* __restrict__ embv,
    const float* __restrict__ lqc_v, const float* __restrict__ lcq_v,
    const float* __restrict__ lqt_v, const float* __restrict__ ltq_v,
    float* __restrict__ o2)
{
  int i = blockIdx.x, h = blockIdx.y, j = threadIdx.x;
  int w = j >> 6;
  __shared__ float qerow[52];
  __shared__ float pws[52];
  __shared__ float pf1s[3], pf2s[3];
  __shared__ float redw[8], redw2[8];
  if (j < RR) qerow[j] = qe[(i*HH+h)*RR + j];
  if (j >= 64 && j < 64+52) pws[j-64] = 0.f;
  if (j >= 192 && j < 195) pf1s[j-192] = 0.f;
  if (j >= 256 && j < 259) pf2s[j-256] = 0.f;

  float lq1[3] = {0,0,0}, lq2[3] = {0,0,0};
  if (i < QQ) {
    #pragma unroll
    for (int f=0; f<3; ++f) {
      lq1[f] = ql[((0*LL + i)*HH + h)*3 + f];
      lq2[f] = ql[((1*LL + i)*HH + h)*3 + f];
    }
  } else if (i < QQ+CCC) {
    #pragma unroll
    for (int f=0; f<3; ++f) lq1[f] = ql[((2*LL + i)*HH + h)*3 + f];
  } else {
    #pragma unroll
    for (int f=0; f<3; ++f) lq1[f] = ql[((3*LL + i)*HH + h)*3 + f];
  }

  // route: 0 = second gather (scat2), 1 = pf1 coeffs, 2 = pf2 coeffs
  float c0=0.f, c1=0.f, c2=0.f; int route; int scat2 = 0;
  if (i < QQ) {
    if (j < QQ) { route = 0; scat2 = 0; }
    else if (j < QQ+CCC) { const float* rr = qcr + (i*CCC + (j-QQ))*3;
      c0=rr[0]; c1=rr[1]; c2=rr[2]; route = 1; }
    else { const float* rr = qtr + (i*TTT + (j-QQ-CCC))*3;
      c0=rr[0]; c1=rr[1]; c2=rr[2]; route = 2; }
  } else {
    if (j < QQ) { const float* rr = (i < QQ+CCC) ? cqr + ((i-QQ)*QQ + j)*3
                                                 : tqr + ((i-QQ-CCC)*QQ + j)*3;
      c0=rr[0]; c1=rr[1]; c2=rr[2]; route = 1; }
    else { route = 0; scat2 = ct[(i-QQ)*(CCC+TTT) + (j-QQ)]; }
  }
  int predv = pred[i*LL + j];
  float s = S[((size_t)h*LL + i)*LL + j];
  __syncthreads();                       // qerow ready (S reads all issued above)

  s += qerow[predv];
  if (route == 0)      s += qerow[scat2];
  else if (route == 1) s += c0*lq1[0] + c1*lq1[1] + c2*lq1[2];
  else                 s += c0*lq2[0] + c1*lq2[1] + c2*lq2[2];
  s *= 0.08838834764831845f;
  if (mask[i*LL + j] == 0) s = -1e9f;

  // wave butterfly max, then 8-wave LDS combine
  float m = s;
  #pragma unroll
  for (int off=32; off>=1; off>>=1) m = fmaxf(m, __shfl_xor(m, off));
  if ((j & 63) == 0) redw[w] = m;
  __syncthreads();
  float mx = redw[0];
  #pragma unroll
  for (int k=1; k<8; ++k) mx = fmaxf(mx, redw[k]);

  float e = __expf(s - mx);
  float sm = e;
  #pragma unroll
  for (int off=32; off>=1; off>>=1) sm += __shfl_xor(sm, off);
  if ((j & 63) == 0) redw2[w] = sm;
  __syncthreads();
  float tot = 0.f;
  #pragma unroll
  for (int k=0; k<8; ++k) tot += redw2[k];
  float p = e * (1.0f/tot);

  ((unsigned short*)S)[((size_t)h*LL + i)*1024 + j] = f2bu(p);

  // pw / pf scatter
  atomicAdd(&pws[predv], p);
  if (route == 0) atomicAdd(&pws[scat2], p);
  float f10=0.f,f11=0.f,f12=0.f,f20=0.f,f21=0.f,f22=0.f;
  if (route == 1) { f10=p*c0; f11=p*c1; f12=p*c2; }
  else if (route == 2) { f20=p*c0; f21=p*c1; f22=p*c2; }
  #pragma unroll
  for (int off=32; off>=1; off>>=1) {
    f10 += __shfl_xor(f10, off); f11 += __shfl_xor(f11, off); f12 += __shfl_xor(f12, off);
    f20 += __shfl_xor(f20, off); f21 += __shfl_xor(f21, off); f22 += __shfl_xor(f22, off);
  }
  if ((j & 63) == 0) {
    atomicAdd(&pf1s[0], f10); atomicAdd(&pf1s[1], f11); atomicAdd(&pf1s[2], f12);
    atomicAdd(&pf2s[0], f20); atomicAdd(&pf2s[1], f21); atomicAdd(&pf2s[2], f22);
  }
  __syncthreads();

  if (j < 128) {
    const float* tab1; const float* tab2 = nullptr;
    if (i < QQ)          { tab1 = lqc_v; tab2 = lqt_v; }
    else if (i < QQ+CCC) { tab1 = lcq_v; }
    else                 { tab1 = ltq_v; }
    int d = j;
    float acc = 0.f;
    #pragma unroll 5
    for (int r = 0; r < RR; ++r) acc += pws[r]*embv[r*128 + d];
    acc += pf1s[0]*tab1[d] + pf1s[1]*tab1[128+d] + pf1s[2]*tab1[256+d];
    if (tab2) acc += pf2s[0]*tab2[d] + pf2s[1]*tab2[128+d] + pf2s[2]*tab2[256+d];
    o2[((size_t)h*LL + i)*DKK + d] = acc;
  }
}

// ---------------- launch ----------------
extern "C" void kernel_launch(void* const* d_in, const int* in_sizes, int n_in,
                              void* d_out, int out_size, void* d_ws, size_t ws_size,
                              hipStream_t stream)
{
  const float* x    = (const float*)d_in[0];
  const float* qcr  = (const float*)d_in[1];
  const float* cqr  = (const float*)d_in[2];
  const float* qtr  = (const float*)d_in[3];
  const float* tqr  = (const float*)d_in[4];
  const int*   ct   = (const int*)d_in[5];
  const int*   pred = (const int*)d_in[6];
  const int*   mask = (const int*)d_in[7];
  const float* embk = (const float*)d_in[8];
  const float* embv = (const float*)d_in[9];
  const float* lqc_k = (const float*)d_in[10];
  const float* lqc_v = (const float*)d_in[11];
  const float* lcq_k = (const float*)d_in[12];
  const float* lcq_v = (const float*)d_in[13];
  const float* lqt_k = (const float*)d_in[14];
  const float* lqt_v = (const float*)d_in[15];
  const float* ltq_k = (const float*)d_in[16];
  const float* ltq_v = (const float*)d_in[17];
  const float* Wq = (const float*)d_in[18]; const float* bq = (const float*)d_in[19];
  const float* Wk = (const float*)d_in[20]; const float* bk = (const float*)d_in[21];
  const float* Wv = (const float*)d_in[22]; const float* bv = (const float*)d_in[23];
  const float* Wo = (const float*)d_in[24]; const float* bo = (const float*)d_in[25];
  const float* ln1_g = (const float*)d_in[26]; const float* ln1_b = (const float*)d_in[27];
  const float* ln2_g = (const float*)d_in[28]; const float* ln2_b = (const float*)d_in[29];
  const float* W1 = (const float*)d_in[30]; const float* b1 = (const float*)d_in[31];
  const float* W2 = (const float*)d_in[32]; const float* b2 = (const float*)d_in[33];
  float* out = (float*)d_out;

  float* wsf = (float*)d_ws;
  float* S    = wsf;                       // [8][512][512] fp32; P bf16 in-place; later FFN hidden
  float* o2   = S + (size_t)HH*LL*LL;      // [8][512][128] fp32
  float* qe   = o2 + (size_t)HH*LL*DKK;    // [L,H,R]
  float* ql   = qe + LL*HH*RR;             // [4,L,H,3]
  unsigned short* ub = (unsigned short*)(ql + 4*LL*HH*3);
  unsigned short* ybuf_b = ub;                     // [L,D]
  unsigned short* obuf_b = ybuf_b + LL*DD;         // [L,D]
  unsigned short* Qh     = obuf_b + LL*DD;         // [H][L][DK]
  unsigned short* Kh     = Qh + LL*DD;             // [H][L][DK]
  unsigned short* Vt     = Kh + LL*DD;             // [H][DK][L]
  unsigned short* PS     = (unsigned short*)S;     // P bf16, ld 1024 shorts
  unsigned short* hidden = (unsigned short*)S;     // [L][FFF] bf16 (after P dead)

  // 1. LN1 -> bf16
  ln_bf16_kernel<<<LL, 256, 0, stream>>>(x, ln1_g, ln1_b, ybuf_b);
  // 2. QKV GEMM (fp32 weights direct) with head scatter: 48x8 = 384 blocks
  gemm_qkv_pl<<<dim3(48, 8), 256, 0, stream>>>(ybuf_b, Wq, Wk, Wv, bq, bk, bv,
                                               Qh, Kh, Vt);
  // 3. fused qe+ql tables
  qtab_kernel<<<dim3(LL, HH), 64, 0, stream>>>(Qh, embk, lqc_k, lqt_k, lcq_k, ltq_k, qe, ql);
  // 4. scores GEMM: S[h] = Qh[h] @ Kh[h]^T   (512 blocks)
  gemm_pl<64,0,0,0,0,0,0><<<dim3(8, 8, 8), 256, 0, stream>>>(
      Qh, DKK, (size_t)LL*DKK, Kh, DKK, (size_t)LL*DKK,
      nullptr, nullptr, 0, 0, S, LL, (size_t)LL*LL, DKK);
  // 5. fused bias+mask+softmax+pw -> P bf16 (in-place) + o2
  softmax_pw_kernel<<<dim3(LL, HH), 512, 0, stream>>>(
      S, qe, ql, qcr, cqr, qtr, tqr, ct, pred, mask,
      embv, lqc_v, lcq_v, lqt_v, ltq_v, o2);
  // 6. PV GEMM + o2 add -> obuf bf16   (BN=32: 4x8x8 = 256 blocks)
  gemm_pl<32,0,0,1,0,1,0><<<dim3(4, 8, 8), 256, 0, stream>>>(
      PS, 1024, (size_t)LL*1024, Vt, LL, (size_t)DKK*LL,
      nullptr, o2, DKK, (size_t)LL*DKK, obuf_b, DD, (size_t)DKK, LL);
  // 7. out-proj (fp32 Wo direct) + residual(x) -> out   (32x8 = 256 blocks)
  gemm_pl<32,1,0,0,0,1,1><<<dim3(32, 8, 1), 256, 0, stream>>>(
      obuf_b, DD, 0, Wo, DD, 0, bo, x, DD, 0, out, DD, 0, DD);
  // 8. LN2 -> bf16, and out += b2 (split-K init)
  ln_bf16_addb_kernel<<<LL, 256, 0, stream>>>(out, ln2_g, ln2_b, b2, ybuf_b);
  // 9. FFN1 relu (fp32 W1 direct) -> hidden bf16  (64x8 = 512 blocks)
  gemm_pl<64,1,0,1,1,0,1><<<dim3(64, 8, 1), 256, 0, stream>>>(
      ybuf_b, DD, 0, W1, DD, 0, b1, nullptr, 0, 0, hidden, FFF, 0, DD);
  // 10. FFN2 split-K x4 (fp32 W2 direct), atomicAdd -> out   (16x8x4 = 512 blocks)
  gemm_pl<64,1,1,0,0,0,0><<<dim3(16, 8, 4), 256, 0, stream>>>(
      hidden, FFF, (size_t)1024, W2, FFF, (size_t)1024,
      nullptr, nullptr, 0, 0, out, DD, 0, 1024);
}

// Round 10
// 244.913 us; speedup vs baseline: 1.1300x; 1.1300x over previous
//
#include <hip/hip_runtime.h>
#include <hip/hip_bf16.h>

#define LL 512
#define DD 1024
#define HH 8
#define DKK 128
#define QQ 256
#define CCC 128
#define TTT 128
#define RR 50
#define FFF 4096
#define KLD 576          // Kh rows per head: 512 keys + 50 embk + 12 ltabs + 2 pad
#define SLD 576          // S row stride (fp32)
#define PLD 1152         // P row stride (shorts) == SLD*2

typedef __attribute__((ext_vector_type(8))) short short8;
typedef __attribute__((ext_vector_type(4))) float float4v;

__device__ __forceinline__ unsigned short f2bu(float f) {
  __hip_bfloat16 h = __float2bfloat16(f);
  unsigned short u; __builtin_memcpy(&u, &h, 2); return u;
}
__device__ __forceinline__ float b2f(unsigned short u) {
  unsigned int v = ((unsigned int)u) << 16;
  float f; __builtin_memcpy(&f, &v, 4); return f;
}
__device__ __forceinline__ int4 cvt8(float4 x, float4 y) {
  int4 o;
  o.x = (int)f2bu(x.x) | ((int)f2bu(x.y) << 16);
  o.y = (int)f2bu(x.z) | ((int)f2bu(x.w) << 16);
  o.z = (int)f2bu(y.x) | ((int)f2bu(y.y) << 16);
  o.w = (int)f2bu(y.z) | ((int)f2bu(y.w) << 16);
  return o;
}

// barrier draining only LDS (lgkmcnt(0)); global loads stay in flight.
__device__ __forceinline__ void lds_barrier() {
  __builtin_amdgcn_sched_barrier(0);
  __builtin_amdgcn_s_waitcnt(0xC07F);
  __builtin_amdgcn_s_barrier();
  __builtin_amdgcn_sched_barrier(0);
}

// explicit-scalar load/store macros: no arrays, no pointer params -> no scratch.
#define LOADSET(A0,A1,B0,B1,F0,F1,F2,F3,itv) { int k0v = (itv) << 6;          \
  A0 = *(const int4*)(Az + (size_t)(bm + r)*lda + k0v + gc*8);                \
  A1 = *(const int4*)(Az + (size_t)(bm + 32 + r)*lda + k0v + gc*8);           \
  if constexpr (!CONVB) {                                                     \
    B0 = *(const int4*)(Bz16 + (size_t)(bnb + r)*ldb + k0v + gc*8);           \
    if constexpr (NB > 1)                                                     \
      B1 = *(const int4*)(Bz16 + (size_t)(bnb + 32 + r)*ldb + k0v + gc*8);    \
  } else {                                                                    \
    F0 = *(const float4*)(Bz32 + (size_t)(bnb + r)*ldb + k0v + gc*8);         \
    F1 = *(const float4*)(Bz32 + (size_t)(bnb + r)*ldb + k0v + gc*8 + 4);     \
    if constexpr (NB > 1) {                                                   \
      F2 = *(const float4*)(Bz32 + (size_t)(bnb + 32 + r)*ldb + k0v + gc*8);  \
      F3 = *(const float4*)(Bz32 + (size_t)(bnb + 32 + r)*ldb + k0v + gc*8 + 4); } } }

#define STORESET2(basep,A0,A1,B0,B1,F0,F1,F2,F3) {                            \
  char* bse = (basep);                                                        \
  *(int4*)(bse + r*128 + sl*16) = A0;                                         \
  *(int4*)(bse + (32 + r)*128 + sl*16) = A1;                                  \
  if constexpr (!CONVB) {                                                     \
    *(int4*)(bse + ABYTES + r*128 + sl*16) = B0;                              \
    if constexpr (NB > 1)                                                     \
      *(int4*)(bse + ABYTES + (32 + r)*128 + sl*16) = B1;                     \
  } else {                                                                    \
    *(int4*)(bse + ABYTES + r*128 + sl*16) = cvt8(F0, F1);                    \
    if constexpr (NB > 1)                                                     \
      *(int4*)(bse + ABYTES + (32 + r)*128 + sl*16) = cvt8(F2, F3); } }

// ---------------- kprep: fill Kh rows 512..575 (embk + l-tables, bf16) ------
__global__ __launch_bounds__(256) void kprep_kernel(
    const float* __restrict__ embk,
    const float* __restrict__ lqc, const float* __restrict__ lqt,
    const float* __restrict__ lcq, const float* __restrict__ ltq,
    unsigned short* __restrict__ Kh)
{
  int g = blockIdx.x*256 + threadIdx.x;       // 8 heads * 64 rows * 128
  if (g >= 8*64*128) return;
  int d = g & 127, rr = (g >> 7) & 63, h = g >> 13;
  float v = 0.f;
  if (rr < 50) v = embk[rr*128 + d];
  else if (rr < 62) {
    int u = rr - 50; int tb = u/3, f = u - tb*3;
    const float* tab = (tb==0) ? lqc : (tb==1) ? lqt : (tb==2) ? lcq : ltq;
    v = tab[f*128 + d];
  }
  Kh[((size_t)h*KLD + 512 + rr)*DKK + d] = f2bu(v);
}

// ---------------- LayerNorm: fp32 in, bf16 out ----------------
__global__ __launch_bounds__(256) void ln_bf16_kernel(const float* __restrict__ x,
    const float* __restrict__ g, const float* __restrict__ b,
    unsigned short* __restrict__ y)
{
  int row = blockIdx.x, t = threadIdx.x;
  const float4 xv = ((const float4*)(x + row*DD))[t];
  float s  = xv.x+xv.y+xv.z+xv.w;
  float ss = xv.x*xv.x+xv.y*xv.y+xv.z*xv.z+xv.w*xv.w;
  __shared__ float rs[256], rss[256];
  rs[t]=s; rss[t]=ss; __syncthreads();
  for (int st=128; st>0; st>>=1){ if (t<st){ rs[t]+=rs[t+st]; rss[t]+=rss[t+st]; } __syncthreads(); }
  float mean = rs[0] * (1.0f/DD);
  float var  = rss[0]*(1.0f/DD) - mean*mean;
  float inv  = rsqrtf(var + 1e-5f);
  float4 gv = ((const float4*)g)[t], bv = ((const float4*)b)[t];
  ushort4 ov;
  ov.x = f2bu((xv.x-mean)*inv*gv.x + bv.x);
  ov.y = f2bu((xv.y-mean)*inv*gv.y + bv.y);
  ov.z = f2bu((xv.z-mean)*inv*gv.z + bv.z);
  ov.w = f2bu((xv.w-mean)*inv*gv.w + bv.w);
  ((ushort4*)(y + row*DD))[t] = ov;
}

// ---------------- LayerNorm + out += b2 (split-K init) ----------------
__global__ __launch_bounds__(256) void ln_bf16_addb_kernel(float* __restrict__ x,
    const float* __restrict__ g, const float* __restrict__ b,
    const float* __restrict__ b2, unsigned short* __restrict__ y)
{
  int row = blockIdx.x, t = threadIdx.x;
  const float4 xv = ((const float4*)(x + row*DD))[t];
  float s  = xv.x+xv.y+xv.z+xv.w;
  float ss = xv.x*xv.x+xv.y*xv.y+xv.z*xv.z+xv.w*xv.w;
  __shared__ float rs[256], rss[256];
  rs[t]=s; rss[t]=ss; __syncthreads();
  for (int st=128; st>0; st>>=1){ if (t<st){ rs[t]+=rs[t+st]; rss[t]+=rss[t+st]; } __syncthreads(); }
  float mean = rs[0] * (1.0f/DD);
  float var  = rss[0]*(1.0f/DD) - mean*mean;
  float inv  = rsqrtf(var + 1e-5f);
  float4 gv = ((const float4*)g)[t], bv = ((const float4*)b)[t];
  ushort4 ov;
  ov.x = f2bu((xv.x-mean)*inv*gv.x + bv.x);
  ov.y = f2bu((xv.y-mean)*inv*gv.y + bv.y);
  ov.z = f2bu((xv.z-mean)*inv*gv.z + bv.z);
  ov.w = f2bu((xv.w-mean)*inv*gv.w + bv.w);
  ((ushort4*)(y + row*DD))[t] = ov;
  float4 b2v = ((const float4*)b2)[t];
  float4 nx; nx.x = xv.x+b2v.x; nx.y = xv.y+b2v.y; nx.z = xv.z+b2v.z; nx.w = xv.w+b2v.w;
  ((float4*)(x + row*DD))[t] = nx;
}

// ======== VGPR-staged pipelined bf16 MFMA GEMM; DEPTH = prefetch depth ======
template<int BN, int DEPTH, int CONVB, int ZK, int OUT_BF16, int RELU, int HAS_SRC, int HAS_BIAS>
__global__ __launch_bounds__(256) void gemm_pl(
    const unsigned short* __restrict__ A, int lda, size_t sAz,
    const void* __restrict__ Bv, int ldb, size_t sBz,
    const float* __restrict__ bias,
    const float* __restrict__ src, int ldsrc, size_t sSz,
    void* __restrict__ Cv, int ldc, size_t sCz,
    int K)
{
  constexpr int BM = 64;
  constexpr int WM = 32, WN = BN/2, FM = 2, FN = WN/16;
  constexpr int NB = BN/32;
  constexpr int ABYTES = BM*128, TILE = ABYTES + BN*128;
  __shared__ char lds[2*TILE];
  int t = threadIdx.x, w = t >> 6, l = t & 63;
  size_t z = blockIdx.z;
  const unsigned short* Az = A + z*sAz;
  const unsigned short* Bz16 = (const unsigned short*)Bv + (CONVB ? 0 : z*sBz);
  const float*          Bz32 = (const float*)Bv + (CONVB ? z*sBz : 0);
  int bm = blockIdx.y*BM, bn = blockIdx.x*BN;
  int bnb = bn;
  int wm = (w>>1)*WM, wn = (w&1)*WN;

  float4v acc[FM][FN];
  #pragma unroll
  for (int m=0;m<FM;++m)
    #pragma unroll
    for (int n=0;n<FN;++n) acc[m][n] = (float4v){0.f,0.f,0.f,0.f};

  int r = t >> 3, sl = t & 7;
  int gc = sl ^ (r & 7);
  int quad = l >> 4, lrow = l & 15;
  const int nit = K >> 6;   // DEPTH==2: nit even; DEPTH==4: nit % 4 == 0

  int4 Aa0, Aa1, Ab0, Ab1;  float4 Af0, Af1, Af2, Af3;
  int4 Ba0, Ba1, Bb0, Bb1;  float4 Bf0, Bf1, Bf2, Bf3;
  int4 Ca0, Ca1, Cb0, Cb1;  float4 Cf0, Cf1, Cf2, Cf3;
  int4 Da0, Da1, Db0, Db1;  float4 Df0, Df1, Df2, Df3;

  auto compute = [&](const char* base) {
    const char* ab = base;
    const char* bb = base + ABYTES;
    #pragma unroll
    for (int step=0; step<2; ++step) {
      int c = step*4 + quad;
      short8 af[FM], bf[FN];
      #pragma unroll
      for (int m=0;m<FM;++m) {
        int Rw = wm + m*16 + lrow;
        af[m] = *(const short8*)(ab + Rw*128 + ((c ^ (Rw & 7))*16));
      }
      #pragma unroll
      for (int n=0;n<FN;++n) {
        int Rw = wn + n*16 + lrow;
        bf[n] = *(const short8*)(bb + Rw*128 + ((c ^ (Rw & 7))*16));
      }
      #pragma unroll
      for (int m=0;m<FM;++m)
        #pragma unroll
        for (int n=0;n<FN;++n)
          acc[m][n] = __builtin_amdgcn_mfma_f32_16x16x32_bf16(af[m], bf[n], acc[m][n], 0, 0, 0);
    }
  };

  if constexpr (DEPTH == 2) {
    LOADSET(Aa0,Aa1,Ab0,Ab1,Af0,Af1,Af2,Af3, 0);
    LOADSET(Ba0,Ba1,Bb0,Bb1,Bf0,Bf1,Bf2,Bf3, 1);
    for (int it = 0; it < nit; it += 2) {
      STORESET2(lds, Aa0,Aa1,Ab0,Ab1,Af0,Af1,Af2,Af3);
      if (it + 2 < nit) LOADSET(Aa0,Aa1,Ab0,Ab1,Af0,Af1,Af2,Af3, it+2);
      lds_barrier();
      compute(lds);
      STORESET2(lds + TILE, Ba0,Ba1,Bb0,Bb1,Bf0,Bf1,Bf2,Bf3);
      if (it + 3 < nit) LOADSET(Ba0,Ba1,Bb0,Bb1,Bf0,Bf1,Bf2,Bf3, it+3);
      lds_barrier();
      compute(lds + TILE);
    }
  } else {
    LOADSET(Aa0,Aa1,Ab0,Ab1,Af0,Af1,Af2,Af3, 0);
    LOADSET(Ba0,Ba1,Bb0,Bb1,Bf0,Bf1,Bf2,Bf3, 1);
    LOADSET(Ca0,Ca1,Cb0,Cb1,Cf0,Cf1,Cf2,Cf3, 2);
    LOADSET(Da0,Da1,Db0,Db1,Df0,Df1,Df2,Df3, 3);
    for (int it = 0; it < nit; it += 4) {
      STORESET2(lds, Aa0,Aa1,Ab0,Ab1,Af0,Af1,Af2,Af3);
      if (it + 4 < nit) LOADSET(Aa0,Aa1,Ab0,Ab1,Af0,Af1,Af2,Af3, it+4);
      lds_barrier();
      compute(lds);
      STORESET2(lds + TILE, Ba0,Ba1,Bb0,Bb1,Bf0,Bf1,Bf2,Bf3);
      if (it + 5 < nit) LOADSET(Ba0,Ba1,Bb0,Bb1,Bf0,Bf1,Bf2,Bf3, it+5);
      lds_barrier();
      compute(lds + TILE);
      STORESET2(lds, Ca0,Ca1,Cb0,Cb1,Cf0,Cf1,Cf2,Cf3);
      if (it + 6 < nit) LOADSET(Ca0,Ca1,Cb0,Cb1,Cf0,Cf1,Cf2,Cf3, it+6);
      lds_barrier();
      compute(lds);
      STORESET2(lds + TILE, Da0,Da1,Db0,Db1,Df0,Df1,Df2,Df3);
      if (it + 7 < nit) LOADSET(Da0,Da1,Db0,Db1,Df0,Df1,Df2,Df3, it+7);
      lds_barrier();
      compute(lds + TILE);
    }
  }

  #pragma unroll
  for (int m=0;m<FM;++m)
    #pragma unroll
    for (int n=0;n<FN;++n)
      #pragma unroll
      for (int rg=0;rg<4;++rg) {
        int row = bm + wm + m*16 + quad*4 + rg;
        int col = bn + wn + n*16 + lrow;
        float vv = acc[m][n][rg];
        if (ZK) {
          atomicAdd(&((float*)Cv)[(size_t)row*ldc + col], vv);
        } else {
          if (HAS_BIAS) vv += bias[col];
          if (HAS_SRC)  vv += src[z*sSz + (size_t)row*ldsrc + col];
          if (RELU) vv = fmaxf(vv, 0.f);
          if (OUT_BF16) ((unsigned short*)Cv)[z*sCz + (size_t)row*ldc + col] = f2bu(vv);
          else          ((float*)Cv)[z*sCz + (size_t)row*ldc + col] = vv;
        }
      }
}

// ---------------- QKV GEMM: fp32 weights direct, DEPTH4, head-scatter -------
__global__ __launch_bounds__(256) void gemm_qkv_pl(
    const unsigned short* __restrict__ A,
    const float* __restrict__ Wq, const float* __restrict__ Wk,
    const float* __restrict__ Wv,
    const float* __restrict__ bq, const float* __restrict__ bk,
    const float* __restrict__ bv,
    unsigned short* __restrict__ Qh, unsigned short* __restrict__ Kh,
    unsigned short* __restrict__ Vt)
{
  constexpr int BN = 64, CONVB = 1;
  constexpr int WM = 32, WN = 32, FM = 2, FN = 2;
  constexpr int NB = 2;
  constexpr int ABYTES = 64*128, TILE = ABYTES + BN*128;
  __shared__ char lds[2*TILE];
  int t = threadIdx.x, w = t >> 6, l = t & 63;
  int bm = blockIdx.y*64, bn = blockIdx.x*BN;
  int wm = (w>>1)*WM, wn = (w&1)*WN;
  const int lda = DD, ldb = DD, nit = DD >> 6;   // 16
  const unsigned short* Az = A;
  int part0 = bn >> 10;
  const float* Bz32 = (part0==0 ? Wq : part0==1 ? Wk : Wv) + (size_t)(bn & 1023)*DD;
  const unsigned short* Bz16 = nullptr; (void)Bz16;
  int bnb = 0;

  float4v acc[FM][FN];
  #pragma unroll
  for (int m=0;m<FM;++m)
    #pragma unroll
    for (int n=0;n<FN;++n) acc[m][n] = (float4v){0.f,0.f,0.f,0.f};

  int r = t >> 3, sl = t & 7;
  int gc = sl ^ (r & 7);
  int quad = l >> 4, lrow = l & 15;

  int4 Aa0, Aa1, Ab0, Ab1;  float4 Af0, Af1, Af2, Af3;
  int4 Ba0, Ba1, Bb0, Bb1;  float4 Bf0, Bf1, Bf2, Bf3;
  int4 Ca0, Ca1, Cb0, Cb1;  float4 Cf0, Cf1, Cf2, Cf3;
  int4 Da0, Da1, Db0, Db1;  float4 Df0, Df1, Df2, Df3;

  auto compute = [&](const char* base) {
    const char* ab = base;
    const char* bb = base + ABYTES;
    #pragma unroll
    for (int step=0; step<2; ++step) {
      int c = step*4 + quad;
      short8 af[FM], bf[FN];
      #pragma unroll
      for (int m=0;m<FM;++m) {
        int Rw = wm + m*16 + lrow;
        af[m] = *(const short8*)(ab + Rw*128 + ((c ^ (Rw & 7))*16));
      }
      #pragma unroll
      for (int n=0;n<FN;++n) {
        int Rw = wn + n*16 + lrow;
        bf[n] = *(const short8*)(bb + Rw*128 + ((c ^ (Rw & 7))*16));
      }
      #pragma unroll
      for (int m=0;m<FM;++m)
        #pragma unroll
        for (int n=0;n<FN;++n)
          acc[m][n] = __builtin_amdgcn_mfma_f32_16x16x32_bf16(af[m], bf[n], acc[m][n], 0, 0, 0);
    }
  };

  LOADSET(Aa0,Aa1,Ab0,Ab1,Af0,Af1,Af2,Af3, 0);
  LOADSET(Ba0,Ba1,Bb0,Bb1,Bf0,Bf1,Bf2,Bf3, 1);
  LOADSET(Ca0,Ca1,Cb0,Cb1,Cf0,Cf1,Cf2,Cf3, 2);
  LOADSET(Da0,Da1,Db0,Db1,Df0,Df1,Df2,Df3, 3);
  for (int it = 0; it < nit; it += 4) {
    STORESET2(lds, Aa0,Aa1,Ab0,Ab1,Af0,Af1,Af2,Af3);
    if (it + 4 < nit) LOADSET(Aa0,Aa1,Ab0,Ab1,Af0,Af1,Af2,Af3, it+4);
    lds_barrier();
    compute(lds);
    STORESET2(lds + TILE, Ba0,Ba1,Bb0,Bb1,Bf0,Bf1,Bf2,Bf3);
    if (it + 5 < nit) LOADSET(Ba0,Ba1,Bb0,Bb1,Bf0,Bf1,Bf2,Bf3, it+5);
    lds_barrier();
    compute(lds + TILE);
    STORESET2(lds, Ca0,Ca1,Cb0,Cb1,Cf0,Cf1,Cf2,Cf3);
    if (it + 6 < nit) LOADSET(Ca0,Ca1,Cb0,Cb1,Cf0,Cf1,Cf2,Cf3, it+6);
    lds_barrier();
    compute(lds);
    STORESET2(lds + TILE, Da0,Da1,Db0,Db1,Df0,Df1,Df2,Df3);
    if (it + 7 < nit) LOADSET(Da0,Da1,Db0,Db1,Df0,Df1,Df2,Df3, it+7);
    lds_barrier();
    compute(lds + TILE);
  }

  #pragma unroll
  for (int m=0;m<FM;++m)
    #pragma unroll
    for (int n=0;n<FN;++n)
      #pragma unroll
      for (int rg=0;rg<4;++rg) {
        int row = bm + wm + m*16 + quad*4 + rg;
        int col = bn + wn + n*16 + lrow;
        int part = col >> 10, hh = (col >> 7) & 7, d = col & 127;
        const float* bp = (part==0) ? bq : (part==1) ? bk : bv;
        float vv = acc[m][n][rg] + bp[col & 1023];
        unsigned short o = f2bu(vv);
        if (part == 0)      Qh[((size_t)hh*LL + row)*DKK + d] = o;
        else if (part == 1) Kh[((size_t)hh*KLD + row)*DKK + d] = o;
        else                Vt[((size_t)hh*DKK + d)*LL + row] = o;
      }
}

// ======== fused softmax + pw/pf + o2, one block per i, all 8 heads ========
__global__ __launch_bounds__(512) void softmax_pw_kernel(
    float* __restrict__ S,                   // [8][512][576] fp32; P bf16 in-place ld 1152
    const float* __restrict__ qcr, const float* __restrict__ cqr,
    const float* __restrict__ qtr, const float* __restrict__ tqr,
    const int* __restrict__ ct,   const int* __restrict__ pred,
    const int* __restrict__ mask,
    const float* __restrict__ embv,
    const float* __restrict__ lqc_v, const float* __restrict__ lcq_v,
    const float* __restrict__ lqt_v, const float* __restrict__ ltq_v,
    float* __restrict__ o2)
{
  int i = blockIdx.x, j = threadIdx.x, w = j >> 6;
  __shared__ float qerow8[8][52];
  __shared__ float lq1s[8][3], lq2s[8][3];
  __shared__ float pws[8][52];
  __shared__ float pf1s[8][3], pf2s[8][3];
  __shared__ float redm[8][8], reds[8][8];

  for (int k = j; k < 8*52; k += 512) ((float*)pws)[k] = 0.f;
  if (j < 24) { ((float*)pf1s)[j] = 0.f; ((float*)pf2s)[j] = 0.f; }
  if (j < 400) {
    int h = j / 50, rr = j - h*50;
    qerow8[h][rr] = S[((size_t)(h*LL + i))*SLD + 512 + rr];
  } else if (j >= 448 && j < 472) {
    int u = j - 448; int h = u / 3, f = u - h*3;
    int base = (i < QQ) ? 562 : (i < QQ+CCC) ? 568 : 571;
    lq1s[h][f] = S[((size_t)(h*LL + i))*SLD + base + f];
    lq2s[h][f] = (i < QQ) ? S[((size_t)(h*LL + i))*SLD + 565 + f] : 0.f;
  }

  int predv = pred[i*LL + j];
  int maskv = mask[i*LL + j];
  float c0=0.f, c1=0.f, c2=0.f; int route; int scat2 = 0;
  if (i < QQ) {
    if (j < QQ) { route = 0; scat2 = 0; }
    else if (j < QQ+CCC) { const float* rr = qcr + (i*CCC + (j-QQ))*3;
      c0=rr[0]; c1=rr[1]; c2=rr[2]; route = 1; }
    else { const float* rr = qtr + (i*TTT + (j-QQ-CCC))*3;
      c0=rr[0]; c1=rr[1]; c2=rr[2]; route = 2; }
  } else {
    if (j < QQ) { const float* rr = (i < QQ+CCC) ? cqr + ((i-QQ)*QQ + j)*3
                                                 : tqr + ((i-QQ-CCC)*QQ + j)*3;
      c0=rr[0]; c1=rr[1]; c2=rr[2]; route = 1; }
    else { route = 0; scat2 = ct[(i-QQ)*(CCC+TTT) + (j-QQ)]; }
  }

  float sv[8];
  #pragma unroll
  for (int h=0; h<8; ++h) sv[h] = S[((size_t)(h*LL + i))*SLD + j];
  __syncthreads();

  #pragma unroll
  for (int h=0; h<8; ++h) {
    float s = sv[h] + qerow8[h][predv];
    if (route == 0)      s += qerow8[h][scat2];
    else if (route == 1) s += c0*lq1s[h][0] + c1*lq1s[h][1] + c2*lq1s[h][2];
    else                 s += c0*lq2s[h][0] + c1*lq2s[h][1] + c2*lq2s[h][2];
    s *= 0.08838834764831845f;
    if (maskv == 0) s = -1e9f;
    sv[h] = s;
  }

  float mv[8];
  #pragma unroll
  for (int h=0; h<8; ++h) mv[h] = sv[h];
  #pragma unroll
  for (int off=32; off>=1; off>>=1) {
    #pragma unroll
    for (int h=0; h<8; ++h) mv[h] = fmaxf(mv[h], __shfl_xor(mv[h], off));
  }
  if ((j & 63) == 0) {
    #pragma unroll
    for (int h=0; h<8; ++h) redm[h][w] = mv[h];
  }
  __syncthreads();
  float ev[8];
  #pragma unroll
  for (int h=0; h<8; ++h) {
    float mx = redm[h][0];
    #pragma unroll
    for (int k=1; k<8; ++k) mx = fmaxf(mx, redm[h][k]);
    ev[h] = __expf(sv[h] - mx);
  }
  float sm[8];
  #pragma unroll
  for (int h=0; h<8; ++h) sm[h] = ev[h];
  #pragma unroll
  for (int off=32; off>=1; off>>=1) {
    #pragma unroll
    for (int h=0; h<8; ++h) sm[h] += __shfl_xor(sm[h], off);
  }
  if ((j & 63) == 0) {
    #pragma unroll
    for (int h=0; h<8; ++h) reds[h][w] = sm[h];
  }
  __syncthreads();
  float pv[8];
  #pragma unroll
  for (int h=0; h<8; ++h) {
    float tot = 0.f;
    #pragma unroll
    for (int k=0; k<8; ++k) tot += reds[h][k];
    pv[h] = ev[h] * (1.0f/tot);
    ((unsigned short*)S)[((size_t)(h*LL + i))*PLD + j] = f2bu(pv[h]);
    atomicAdd(&pws[h][predv], pv[h]);
    if (route == 0) atomicAdd(&pws[h][scat2], pv[h]);
  }
  if (route == 1) {
    #pragma unroll
    for (int h=0; h<8; ++h) {
      float f0 = pv[h]*c0, f1 = pv[h]*c1, f2 = pv[h]*c2;
      #pragma unroll
      for (int off=32; off>=1; off>>=1) {
        f0 += __shfl_xor(f0, off); f1 += __shfl_xor(f1, off); f2 += __shfl_xor(f2, off);
      }
      if ((j & 63) == 0) {
        atomicAdd(&pf1s[h][0], f0); atomicAdd(&pf1s[h][1], f1); atomicAdd(&pf1s[h][2], f2);
      }
    }
  } else if (route == 2) {
    #pragma unroll
    for (int h=0; h<8; ++h) {
      float f0 = pv[h]*c0, f1 = pv[h]*c1, f2 = pv[h]*c2;
      #pragma unroll
      for (int off=32; off>=1; off>>=1) {
        f0 += __shfl_xor(f0, off); f1 += __shfl_xor(f1, off); f2 += __shfl_xor(f2, off);
      }
      if ((j & 63) == 0) {
        atomicAdd(&pf2s[h][0], f0); atomicAdd(&pf2s[h][1], f1); atomicAdd(&pf2s[h][2], f2);
      }
    }
  }
  __syncthreads();

  // epilogue: o2[h][i][d] for 8 heads x 128 d, 2 outputs per thread
  {
    int h0 = j >> 7;          // 0..3
    int d  = j & 127;
    const float* tab1; const float* tab2 = nullptr;
    if (i < QQ)          { tab1 = lqc_v; tab2 = lqt_v; }
    else if (i < QQ+CCC) { tab1 = lcq_v; }
    else                 { tab1 = ltq_v; }
    float accA = 0.f, accB = 0.f;
    #pragma unroll 5
    for (int rr = 0; rr < RR; ++rr) {
      float evv = embv[rr*128 + d];
      accA += pws[h0][rr]*evv; accB += pws[h0+4][rr]*evv;
    }
    float t0 = tab1[d], t1 = tab1[128+d], t2 = tab1[256+d];
    accA += pf1s[h0][0]*t0 + pf1s[h0][1]*t1 + pf1s[h0][2]*t2;
    accB += pf1s[h0+4][0]*t0 + pf1s[h0+4][1]*t1 + pf1s[h0+4][2]*t2;
    if (tab2) {
      float u0 = tab2[d], u1 = tab2[128+d], u2 = tab2[256+d];
      accA += pf2s[h0][0]*u0 + pf2s[h0][1]*u1 + pf2s[h0][2]*u2;
      accB += pf2s[h0+4][0]*u0 + pf2s[h0+4][1]*u1 + pf2s[h0+4][2]*u2;
    }
    o2[((size_t)(h0*LL) + i)*DKK + d] = accA;
    o2[((size_t)((h0+4)*LL) + i)*DKK + d] = accB;
  }
}

// ---------------- launch ----------------
extern "C" void kernel_launch(void* const* d_in, const int* in_sizes, int n_in,
                              void* d_out, int out_size, void* d_ws, size_t ws_size,
                              hipStream_t stream)
{
  const float* x    = (const float*)d_in[0];
  const float* qcr  = (const float*)d_in[1];
  const float* cqr  = (const float*)d_in[2];
  const float* qtr  = (const float*)d_in[3];
  const float* tqr  = (const float*)d_in[4];
  const int*   ct   = (const int*)d_in[5];
  const int*   pred = (const int*)d_in[6];
  const int*   mask = (const int*)d_in[7];
  const float* embk = (const float*)d_in[8];
  const float* embv = (const float*)d_in[9];
  const float* lqc_k = (const float*)d_in[10];
  const float* lqc_v = (const float*)d_in[11];
  const float* lcq_k = (const float*)d_in[12];
  const float* lcq_v = (const float*)d_in[13];
  const float* lqt_k = (const float*)d_in[14];
  const float* lqt_v = (const float*)d_in[15];
  const float* ltq_k = (const float*)d_in[16];
  const float* ltq_v = (const float*)d_in[17];
  const float* Wq = (const float*)d_in[18]; const float* bq = (const float*)d_in[19];
  const float* Wk = (const float*)d_in[20]; const float* bk = (const float*)d_in[21];
  const float* Wv = (const float*)d_in[22]; const float* bv = (const float*)d_in[23];
  const float* Wo = (const float*)d_in[24]; const float* bo = (const float*)d_in[25];
  const float* ln1_g = (const float*)d_in[26]; const float* ln1_b = (const float*)d_in[27];
  const float* ln2_g = (const float*)d_in[28]; const float* ln2_b = (const float*)d_in[29];
  const float* W1 = (const float*)d_in[30]; const float* b1 = (const float*)d_in[31];
  const float* W2 = (const float*)d_in[32]; const float* b2 = (const float*)d_in[33];
  float* out = (float*)d_out;

  float* wsf = (float*)d_ws;
  float* S    = wsf;                          // [8][512][576] fp32; P bf16 in-place; later FFN hidden
  float* o2   = S + (size_t)HH*LL*SLD;        // [8][512][128] fp32
  unsigned short* ub = (unsigned short*)(o2 + (size_t)HH*LL*DKK);
  unsigned short* ybuf_b = ub;                        // [L,D]
  unsigned short* obuf_b = ybuf_b + LL*DD;            // [L,D]
  unsigned short* Qh     = obuf_b + LL*DD;            // [H][512][128]
  unsigned short* Kh     = Qh + (size_t)HH*LL*DKK;    // [H][576][128]
  unsigned short* Vt     = Kh + (size_t)HH*KLD*DKK;   // [H][128][512]
  unsigned short* PS     = (unsigned short*)S;        // P bf16, ld 1152
  unsigned short* hidden = (unsigned short*)S;        // [L][FFF] bf16 (after P dead)

  // 1. fill Kh bias rows (independent of everything)
  kprep_kernel<<<(8*64*128 + 255)/256, 256, 0, stream>>>(
      embk, lqc_k, lqt_k, lcq_k, ltq_k, Kh);
  // 2. LN1 -> bf16
  ln_bf16_kernel<<<LL, 256, 0, stream>>>(x, ln1_g, ln1_b, ybuf_b);
  // 3. QKV GEMM (fp32 weights direct, depth-4) with head scatter
  gemm_qkv_pl<<<dim3(48, 8), 256, 0, stream>>>(ybuf_b, Wq, Wk, Wv, bq, bk, bv,
                                               Qh, Kh, Vt);
  // 4. scores GEMM: S[h] = Qh[h] @ KhExt[h]^T  (576 cols: scores + qe + lq dots)
  gemm_pl<64,2,0,0,0,0,0,0><<<dim3(9, 8, 8), 256, 0, stream>>>(
      Qh, DKK, (size_t)LL*DKK, Kh, DKK, (size_t)KLD*DKK,
      nullptr, nullptr, 0, 0, S, SLD, (size_t)LL*SLD, DKK);
  // 5. fused softmax + pw + o2 (one block per i)
  softmax_pw_kernel<<<LL, 512, 0, stream>>>(
      S, qcr, cqr, qtr, tqr, ct, pred, mask,
      embv, lqc_v, lcq_v, lqt_v, ltq_v, o2);
  // 6. PV GEMM + o2 add -> obuf bf16  (depth-4, nit=8)
  gemm_pl<32,4,0,0,1,0,1,0><<<dim3(4, 8, 8), 256, 0, stream>>>(
      PS, PLD, (size_t)LL*PLD, Vt, LL, (size_t)DKK*LL,
      nullptr, o2, DKK, (size_t)LL*DKK, obuf_b, DD, (size_t)DKK, LL);
  // 7. out-proj (fp32 Wo direct, depth-4) + residual(x) -> out
  gemm_pl<32,4,1,0,0,0,1,1><<<dim3(32, 8, 1), 256, 0, stream>>>(
      obuf_b, DD, 0, Wo, DD, 0, bo, x, DD, 0, out, DD, 0, DD);
  // 8. LN2 -> bf16, and out += b2 (split-K init)
  ln_bf16_addb_kernel<<<LL, 256, 0, stream>>>(out, ln2_g, ln2_b, b2, ybuf_b);
  // 9. FFN1 relu (fp32 W1 direct, depth-4) -> hidden bf16
  gemm_pl<64,4,1,0,1,1,0,1><<<dim3(64, 8, 1), 256, 0, stream>>>(
      ybuf_b, DD, 0, W1, DD, 0, b1, nullptr, 0, 0, hidden, FFF, 0, DD);
  // 10. FFN2 split-K x4 (fp32 W2 direct, depth-4), atomicAdd -> out
  gemm_pl<64,4,1,1,0,0,0,0><<<dim3(16, 8, 4), 256, 0, stream>>>(
      hidden, FFF, (size_t)1024, W2, FFF, (size_t)1024,
      nullptr, nullptr, 0, 0, out, DD, 0, 1024);
}